// Round 1
// baseline (104.925 us; speedup 1.0000x reference)
//
#include <hip/hip_runtime.h>

// Problem constants (B=1)
constexpr int T_N = 256;   // sequence length
constexpr int C_N = 512;   // channels

// out = ((x @ Wv1^T) * (x @ Wv2^T)) @ Wc^T
// (mask reduces third-order attention to one-hot at (i,i,i); softmax exact 1)

constexpr int BM = 32, BN = 32, BK = 32, PAD = 2;

// Kernel 1: y[m][n] = (sum_k x[m][k]*Wv1[n][k]) * (sum_k x[m][k]*Wv2[n][k])
__global__ __launch_bounds__(256) void vprod_gemm(
    const float* __restrict__ x,     // (T_N, C_N)
    const float* __restrict__ Wv1,   // (C_N, C_N) row-major
    const float* __restrict__ Wv2,   // (C_N, C_N)
    float* __restrict__ y)           // (T_N, C_N)
{
    __shared__ float As [BK][BM + PAD];   // transposed: As[k][m]
    __shared__ float B1s[BK][BN + PAD];   // B1s[k][n]
    __shared__ float B2s[BK][BN + PAD];

    const int tid = threadIdx.x;
    const int tx  = tid & 15;       // output col group
    const int ty  = tid >> 4;       // output row group
    const int m0  = blockIdx.x * BM;
    const int n0  = blockIdx.y * BN;

    const int lr  = tid >> 3;       // load row within tile, 0..31
    const int lc4 = tid & 7;        // float4 column, 0..7

    float acc1[2][2] = {{0.f,0.f},{0.f,0.f}};
    float acc2[2][2] = {{0.f,0.f},{0.f,0.f}};

    for (int kt = 0; kt < C_N; kt += BK) {
        float4 av  = *(const float4*)&x  [(m0 + lr) * C_N + kt + lc4 * 4];
        float4 b1v = *(const float4*)&Wv1[(n0 + lr) * C_N + kt + lc4 * 4];
        float4 b2v = *(const float4*)&Wv2[(n0 + lr) * C_N + kt + lc4 * 4];
        __syncthreads();   // previous iteration done reading LDS
        As [lc4*4+0][lr] = av.x;  As [lc4*4+1][lr] = av.y;
        As [lc4*4+2][lr] = av.z;  As [lc4*4+3][lr] = av.w;
        B1s[lc4*4+0][lr] = b1v.x; B1s[lc4*4+1][lr] = b1v.y;
        B1s[lc4*4+2][lr] = b1v.z; B1s[lc4*4+3][lr] = b1v.w;
        B2s[lc4*4+0][lr] = b2v.x; B2s[lc4*4+1][lr] = b2v.y;
        B2s[lc4*4+2][lr] = b2v.z; B2s[lc4*4+3][lr] = b2v.w;
        __syncthreads();
        #pragma unroll
        for (int kk = 0; kk < BK; ++kk) {
            float2 a  = *(const float2*)&As [kk][ty * 2];
            float2 b1 = *(const float2*)&B1s[kk][tx * 2];
            float2 b2 = *(const float2*)&B2s[kk][tx * 2];
            acc1[0][0] += a.x * b1.x; acc1[0][1] += a.x * b1.y;
            acc1[1][0] += a.y * b1.x; acc1[1][1] += a.y * b1.y;
            acc2[0][0] += a.x * b2.x; acc2[0][1] += a.x * b2.y;
            acc2[1][0] += a.y * b2.x; acc2[1][1] += a.y * b2.y;
        }
    }

    #pragma unroll
    for (int i = 0; i < 2; ++i)
        #pragma unroll
        for (int j = 0; j < 2; ++j)
            y[(m0 + ty*2 + i) * C_N + (n0 + tx*2 + j)] = acc1[i][j] * acc2[i][j];
}

// Kernel 2: out[m][n] = sum_k y[m][k] * Wc[n][k]
__global__ __launch_bounds__(256) void out_gemm(
    const float* __restrict__ y,     // (T_N, C_N)
    const float* __restrict__ Wc,    // (C_N, C_N)
    float* __restrict__ out)         // (T_N, C_N)
{
    __shared__ float As[BK][BM + PAD];
    __shared__ float Bs[BK][BN + PAD];

    const int tid = threadIdx.x;
    const int tx  = tid & 15;
    const int ty  = tid >> 4;
    const int m0  = blockIdx.x * BM;
    const int n0  = blockIdx.y * BN;

    const int lr  = tid >> 3;
    const int lc4 = tid & 7;

    float acc[2][2] = {{0.f,0.f},{0.f,0.f}};

    for (int kt = 0; kt < C_N; kt += BK) {
        float4 av = *(const float4*)&y [(m0 + lr) * C_N + kt + lc4 * 4];
        float4 bv = *(const float4*)&Wc[(n0 + lr) * C_N + kt + lc4 * 4];
        __syncthreads();
        As[lc4*4+0][lr] = av.x; As[lc4*4+1][lr] = av.y;
        As[lc4*4+2][lr] = av.z; As[lc4*4+3][lr] = av.w;
        Bs[lc4*4+0][lr] = bv.x; Bs[lc4*4+1][lr] = bv.y;
        Bs[lc4*4+2][lr] = bv.z; Bs[lc4*4+3][lr] = bv.w;
        __syncthreads();
        #pragma unroll
        for (int kk = 0; kk < BK; ++kk) {
            float2 a = *(const float2*)&As[kk][ty * 2];
            float2 b = *(const float2*)&Bs[kk][tx * 2];
            acc[0][0] += a.x * b.x; acc[0][1] += a.x * b.y;
            acc[1][0] += a.y * b.x; acc[1][1] += a.y * b.y;
        }
    }

    #pragma unroll
    for (int i = 0; i < 2; ++i)
        #pragma unroll
        for (int j = 0; j < 2; ++j)
            out[(m0 + ty*2 + i) * C_N + (n0 + tx*2 + j)] = acc[i][j];
}

extern "C" void kernel_launch(void* const* d_in, const int* in_sizes, int n_in,
                              void* d_out, int out_size, void* d_ws, size_t ws_size,
                              hipStream_t stream) {
    // inputs: 0=x, 1=Wq, 2=Wk1, 3=Wk2, 4=Wv1, 5=Wv2, 6=Wc  (all fp32)
    const float* x   = (const float*)d_in[0];
    const float* Wv1 = (const float*)d_in[4];
    const float* Wv2 = (const float*)d_in[5];
    const float* Wc  = (const float*)d_in[6];
    float*       out = (float*)d_out;
    float*       y   = (float*)d_ws;   // T_N*C_N fp32 = 512 KiB scratch

    dim3 grid(T_N / BM, C_N / BN);     // 8 x 16 = 128 blocks
    vprod_gemm<<<grid, 256, 0, stream>>>(x, Wv1, Wv2, y);
    out_gemm  <<<grid, 256, 0, stream>>>(y, Wc, out);
}

// Round 2
// 84.407 us; speedup vs baseline: 1.2431x; 1.2431x over previous
//
#include <hip/hip_runtime.h>

// B=1, T=256, C=512. Mask of the 3rd-order attention is one-hot at (i,i,i),
// softmax is exactly 1 there => out = ((x@Wv1^T) * (x@Wv2^T)) @ Wc^T.
// Strategy: bf16 MFMA (16x16x32), fragments loaded straight from global
// (all operands K-major), fp32->bf16 convert in-register. No LDS.

constexpr int T_N = 256;
constexpr int C_N = 512;

typedef short bf16x8 __attribute__((ext_vector_type(8)));
typedef float f32x4  __attribute__((ext_vector_type(4)));

__device__ __forceinline__ unsigned short f2bf(float f) {
    unsigned u = __float_as_uint(f);
    return (unsigned short)((u + 0x7FFFu + ((u >> 16) & 1u)) >> 16);  // RNE
}

// Load an 8-wide bf16 fragment (one lane's A or B operand piece) from an
// fp32 row-major (rows x 512) matrix: row, k-base (multiple of 8).
__device__ __forceinline__ bf16x8 frag_from_f32(const float* __restrict__ p,
                                                int row, int kbase) {
    const float4 a = *(const float4*)(p + row * C_N + kbase);
    const float4 b = *(const float4*)(p + row * C_N + kbase + 4);
    bf16x8 f;
    f[0] = (short)f2bf(a.x); f[1] = (short)f2bf(a.y);
    f[2] = (short)f2bf(a.z); f[3] = (short)f2bf(a.w);
    f[4] = (short)f2bf(b.x); f[5] = (short)f2bf(b.y);
    f[6] = (short)f2bf(b.z); f[7] = (short)f2bf(b.w);
    return f;
}

// Kernel 1: y_bf16[m][n] = bf16( (x@Wv1^T)[m][n] * (x@Wv2^T)[m][n] )
// One 16x16 output tile per wave; 16x32 = 512 wave-tiles.
__global__ __launch_bounds__(256) void k1_vprod(
    const float* __restrict__ x,     // (256,512)
    const float* __restrict__ Wv1,   // (512,512) row-major (n,k)
    const float* __restrict__ Wv2,
    unsigned short* __restrict__ y)  // (256,512) bf16 bits
{
    const int lane = threadIdx.x & 63;
    const int wid  = blockIdx.x * 4 + (threadIdx.x >> 6);   // 0..511
    const int m0 = (wid & 15) << 4;    // 16 m-tiles
    const int n0 = (wid >> 4) << 4;    // 32 n-tiles
    const int frow = lane & 15;
    const int fk   = (lane >> 4) << 3;

    f32x4 acc1 = {0.f, 0.f, 0.f, 0.f};
    f32x4 acc2 = {0.f, 0.f, 0.f, 0.f};

    #pragma unroll
    for (int kt = 0; kt < C_N; kt += 32) {
        bf16x8 af = frag_from_f32(x,   m0 + frow, kt + fk);
        bf16x8 b1 = frag_from_f32(Wv1, n0 + frow, kt + fk);
        bf16x8 b2 = frag_from_f32(Wv2, n0 + frow, kt + fk);
        acc1 = __builtin_amdgcn_mfma_f32_16x16x32_bf16(af, b1, acc1, 0, 0, 0);
        acc2 = __builtin_amdgcn_mfma_f32_16x16x32_bf16(af, b2, acc2, 0, 0, 0);
    }

    // C/D layout (m89): col = lane&15, row = (lane>>4)*4 + reg
    const int orow = m0 + ((lane >> 4) << 2);
    const int ocol = n0 + (lane & 15);
    #pragma unroll
    for (int r = 0; r < 4; ++r)
        y[(orow + r) * C_N + ocol] = f2bf(acc1[r] * acc2[r]);
}

// Kernel 2: out[m][n] = sum_k y[m][k] * Wc[n][k]   (A already bf16)
__global__ __launch_bounds__(256) void k2_proj(
    const unsigned short* __restrict__ y,  // (256,512) bf16 bits
    const float* __restrict__ Wc,          // (512,512) (n,k)
    float* __restrict__ out)               // (256,512) fp32
{
    const int lane = threadIdx.x & 63;
    const int wid  = blockIdx.x * 4 + (threadIdx.x >> 6);
    const int m0 = (wid & 15) << 4;
    const int n0 = (wid >> 4) << 4;
    const int frow = lane & 15;
    const int fk   = (lane >> 4) << 3;

    f32x4 acc = {0.f, 0.f, 0.f, 0.f};

    #pragma unroll
    for (int kt = 0; kt < C_N; kt += 32) {
        bf16x8 af = *(const bf16x8*)(y + (m0 + frow) * C_N + kt + fk); // 16B aligned
        bf16x8 bf = frag_from_f32(Wc, n0 + frow, kt + fk);
        acc = __builtin_amdgcn_mfma_f32_16x16x32_bf16(af, bf, acc, 0, 0, 0);
    }

    const int orow = m0 + ((lane >> 4) << 2);
    const int ocol = n0 + (lane & 15);
    #pragma unroll
    for (int r = 0; r < 4; ++r)
        out[(orow + r) * C_N + ocol] = acc[r];
}

extern "C" void kernel_launch(void* const* d_in, const int* in_sizes, int n_in,
                              void* d_out, int out_size, void* d_ws, size_t ws_size,
                              hipStream_t stream) {
    // inputs: 0=x, 1=Wq, 2=Wk1, 3=Wk2, 4=Wv1, 5=Wv2, 6=Wc (all fp32)
    const float* x   = (const float*)d_in[0];
    const float* Wv1 = (const float*)d_in[4];
    const float* Wv2 = (const float*)d_in[5];
    const float* Wc  = (const float*)d_in[6];
    float*       out = (float*)d_out;
    unsigned short* y = (unsigned short*)d_ws;   // 256x512 bf16 = 256 KiB

    k1_vprod<<<128, 256, 0, stream>>>(x, Wv1, Wv2, y);
    k2_proj <<<128, 256, 0, stream>>>(y, Wc, out);
}

// Round 3
// 80.053 us; speedup vs baseline: 1.3107x; 1.0544x over previous
//
#include <hip/hip_runtime.h>

// B=1, T=256, C=512. Mask of the 3rd-order attention is one-hot at (i,i,i),
// softmax is exactly 1 there => out = ((x@Wv1^T) * (x@Wv2^T)) @ Wc^T.
// bf16 MFMA (16x16x32), fragments straight from global (all operands K-major),
// fp32->bf16 RNE in-register, no LDS. 512 wave-tiles spread over 256 CUs
// (256 blocks x 128 threads = 2 waves/CU) for TLP.

constexpr int T_N = 256;
constexpr int C_N = 512;

typedef short bf16x8 __attribute__((ext_vector_type(8)));
typedef float f32x4  __attribute__((ext_vector_type(4)));

__device__ __forceinline__ unsigned short f2bf(float f) {
    unsigned u = __float_as_uint(f);
    return (unsigned short)((u + 0x7FFFu + ((u >> 16) & 1u)) >> 16);  // RNE
}

__device__ __forceinline__ bf16x8 frag_from_f32(const float* __restrict__ p,
                                                int row, int kbase) {
    const float4 a = *(const float4*)(p + row * C_N + kbase);
    const float4 b = *(const float4*)(p + row * C_N + kbase + 4);
    bf16x8 f;
    f[0] = (short)f2bf(a.x); f[1] = (short)f2bf(a.y);
    f[2] = (short)f2bf(a.z); f[3] = (short)f2bf(a.w);
    f[4] = (short)f2bf(b.x); f[5] = (short)f2bf(b.y);
    f[6] = (short)f2bf(b.z); f[7] = (short)f2bf(b.w);
    return f;
}

// Kernel 1: y_bf16[m][n] = bf16( (x@Wv1^T)[m][n] * (x@Wv2^T)[m][n] )
// One 16x16 output tile per wave; 512 wave-tiles; 2 waves/block, 256 blocks.
__global__ __launch_bounds__(128) void k1_vprod(
    const float* __restrict__ x,     // (256,512)
    const float* __restrict__ Wv1,   // (512,512) row-major (n,k)
    const float* __restrict__ Wv2,
    unsigned short* __restrict__ y)  // (256,512) bf16 bits
{
    const int lane = threadIdx.x & 63;
    const int wid  = blockIdx.x * 2 + (threadIdx.x >> 6);   // 0..511
    const int m0 = (wid & 15) << 4;    // 16 m-tiles
    const int n0 = (wid >> 4) << 4;    // 32 n-tiles
    const int frow = lane & 15;
    const int fk   = (lane >> 4) << 3;

    f32x4 acc1 = {0.f, 0.f, 0.f, 0.f};
    f32x4 acc2 = {0.f, 0.f, 0.f, 0.f};

    #pragma unroll
    for (int kt = 0; kt < C_N; kt += 32) {
        bf16x8 af = frag_from_f32(x,   m0 + frow, kt + fk);
        bf16x8 b1 = frag_from_f32(Wv1, n0 + frow, kt + fk);
        bf16x8 b2 = frag_from_f32(Wv2, n0 + frow, kt + fk);
        acc1 = __builtin_amdgcn_mfma_f32_16x16x32_bf16(af, b1, acc1, 0, 0, 0);
        acc2 = __builtin_amdgcn_mfma_f32_16x16x32_bf16(af, b2, acc2, 0, 0, 0);
    }

    // C/D layout (m89): col = lane&15, row = (lane>>4)*4 + reg
    const int orow = m0 + ((lane >> 4) << 2);
    const int ocol = n0 + (lane & 15);
    #pragma unroll
    for (int r = 0; r < 4; ++r)
        y[(orow + r) * C_N + ocol] = f2bf(acc1[r] * acc2[r]);
}

// Kernel 2: out[m][n] = sum_k y[m][k] * Wc[n][k]   (A already bf16)
__global__ __launch_bounds__(128) void k2_proj(
    const unsigned short* __restrict__ y,  // (256,512) bf16 bits
    const float* __restrict__ Wc,          // (512,512) (n,k)
    float* __restrict__ out)               // (256,512) fp32
{
    const int lane = threadIdx.x & 63;
    const int wid  = blockIdx.x * 2 + (threadIdx.x >> 6);
    const int m0 = (wid & 15) << 4;
    const int n0 = (wid >> 4) << 4;
    const int frow = lane & 15;
    const int fk   = (lane >> 4) << 3;

    f32x4 acc = {0.f, 0.f, 0.f, 0.f};

    #pragma unroll
    for (int kt = 0; kt < C_N; kt += 32) {
        bf16x8 af = *(const bf16x8*)(y + (m0 + frow) * C_N + kt + fk);
        bf16x8 bf = frag_from_f32(Wc, n0 + frow, kt + fk);
        acc = __builtin_amdgcn_mfma_f32_16x16x32_bf16(af, bf, acc, 0, 0, 0);
    }

    const int orow = m0 + ((lane >> 4) << 2);
    const int ocol = n0 + (lane & 15);
    #pragma unroll
    for (int r = 0; r < 4; ++r)
        out[(orow + r) * C_N + ocol] = acc[r];
}

extern "C" void kernel_launch(void* const* d_in, const int* in_sizes, int n_in,
                              void* d_out, int out_size, void* d_ws, size_t ws_size,
                              hipStream_t stream) {
    // inputs: 0=x, 1=Wq, 2=Wk1, 3=Wk2, 4=Wv1, 5=Wv2, 6=Wc (all fp32)
    const float* x   = (const float*)d_in[0];
    const float* Wv1 = (const float*)d_in[4];
    const float* Wv2 = (const float*)d_in[5];
    const float* Wc  = (const float*)d_in[6];
    float*       out = (float*)d_out;
    unsigned short* y = (unsigned short*)d_ws;   // 256x512 bf16 = 256 KiB

    k1_vprod<<<256, 128, 0, stream>>>(x, Wv1, Wv2, y);
    k2_proj <<<256, 128, 0, stream>>>(y, Wc, out);
}